// Round 1
// baseline (588.453 us; speedup 1.0000x reference)
//
#include <hip/hip_runtime.h>
#include <hip/hip_bf16.h>
#include <stdint.h>

// Problem: B=32, S=2048, DK=DV=64, fp32 in/out.
// out = [output (B,S,64) | attn (B,S,S)] concatenated fp32.
// Two-pass MFMA attention:
//   prepass: detect mask dtype; cast K->bf16 (ws); transpose-cast V -> Vt bf16 (ws)
//   main: per 16-query wave: pass1 QK^T -> row sum of exp; pass2 recompute,
//         write attn, PV via mfma_f32_16x16x32_bf16.

#define B_ 32
#define S_ 2048
#define D_ 64

typedef float   f32x4  __attribute__((ext_vector_type(4)));
typedef __bf16  bf16x8 __attribute__((ext_vector_type(8)));
typedef unsigned short u16x4 __attribute__((ext_vector_type(4)));

__device__ __forceinline__ unsigned short f2bf(float f) {
  unsigned u = __float_as_uint(f);
  u = (u + 0x7FFFu + ((u >> 16) & 1u)) >> 16;   // RNE
  return (unsigned short)u;
}

// ---------------- mask dtype detection ----------------
// flag: 0 = uint8 (numpy bool), 1 = int32 (0/1), 2 = float32 (0.0/1.0)
__global__ void detect_mask(const unsigned* __restrict__ m, int* __restrict__ flag) {
  if (threadIdx.x == 0 && blockIdx.x == 0) {
    int all01 = 1, allf = 1;
    for (int i = 0; i < 64; ++i) {
      unsigned w = m[i];
      all01 &= (w <= 1u);
      allf  &= (w == 0u || w == 0x3F800000u);
    }
    *flag = all01 ? 1 : (allf ? 2 : 0);
  }
}

// ---------------- K fp32 -> bf16 cast ----------------
__global__ void cast_k(const float* __restrict__ K, unsigned short* __restrict__ Kbf) {
  size_t i = ((size_t)blockIdx.x * 256 + threadIdx.x) * 4;
  f32x4 v = *reinterpret_cast<const f32x4*>(K + i);
  u16x4 o;
  o[0] = f2bf(v[0]); o[1] = f2bf(v[1]); o[2] = f2bf(v[2]); o[3] = f2bf(v[3]);
  *reinterpret_cast<u16x4*>(Kbf + i) = o;
}

// ---------------- V -> Vt (d-major) bf16 transpose ----------------
__global__ void transpose_v(const float* __restrict__ V, unsigned short* __restrict__ Vt) {
  __shared__ float tile[32][33];
  int b = blockIdx.z, k0 = blockIdx.x * 32, d0 = blockIdx.y * 32;
  int tx = threadIdx.x, ty = threadIdx.y;
  const float* src = V + ((size_t)b * S_ + k0) * D_ + d0;
  for (int r = 0; r < 4; ++r) {
    int yy = ty + r * 8;
    tile[yy][tx] = src[(size_t)yy * D_ + tx];
  }
  __syncthreads();
  unsigned short* dst = Vt + ((size_t)b * D_ + d0) * S_ + k0;
  for (int r = 0; r < 4; ++r) {
    int yy = ty + r * 8;
    dst[(size_t)yy * S_ + tx] = f2bf(tile[tx][yy]);
  }
}

// ---------------- main attention ----------------
template <typename MT>
__device__ __forceinline__ void attn_run(
    const float* __restrict__ Qb, const unsigned short* __restrict__ Kb,
    const MT* __restrict__ Mb, const unsigned short* __restrict__ Vtb,
    float* __restrict__ outO, float* __restrict__ outP,
    int q0, int lane, unsigned short* __restrict__ Pl /* [16][40] this wave */) {
  const int lo = lane & 15, hi = lane >> 4;

  // A-frags: Q rows = lo, k = kb*32 + hi*8 + j  (same per-lane k-pattern as B)
  bf16x8 aq[2];
  {
    const float* qr = Qb + (size_t)(q0 + lo) * D_;
#pragma unroll
    for (int kb = 0; kb < 2; ++kb) {
      const float* p = qr + kb * 32 + hi * 8;
      f32x4 x = *reinterpret_cast<const f32x4*>(p);
      f32x4 y = *reinterpret_cast<const f32x4*>(p + 4);
      bf16x8 a;
      a[0] = (__bf16)x[0]; a[1] = (__bf16)x[1]; a[2] = (__bf16)x[2]; a[3] = (__bf16)x[3];
      a[4] = (__bf16)y[0]; a[5] = (__bf16)y[1]; a[6] = (__bf16)y[2]; a[7] = (__bf16)y[3];
      aq[kb] = a;
    }
  }

  // D layout: col = lane&15 (key), row = (lane>>4)*4 + reg (query)
  size_t mrow[4];
  float* prow[4];
#pragma unroll
  for (int i = 0; i < 4; ++i) {
    int q = q0 + hi * 4 + i;
    mrow[i] = (size_t)q * S_;
    prow[i] = outP + (size_t)q * S_;
  }

  // ---- pass 1: denominators ----
  float lsum[4] = {0.f, 0.f, 0.f, 0.f};
  for (int kc = 0; kc < S_ / 16; ++kc) {
    int key = kc * 16 + lo;
    const unsigned short* kr = Kb + (size_t)key * D_ + hi * 8;
    bf16x8 b0 = *reinterpret_cast<const bf16x8*>(kr);
    bf16x8 b1 = *reinterpret_cast<const bf16x8*>(kr + 32);
    f32x4 acc = {0.f, 0.f, 0.f, 0.f};
    acc = __builtin_amdgcn_mfma_f32_16x16x32_bf16(aq[0], b0, acc, 0, 0, 0);
    acc = __builtin_amdgcn_mfma_f32_16x16x32_bf16(aq[1], b1, acc, 0, 0, 0);
#pragma unroll
    for (int i = 0; i < 4; ++i) {
      bool mk = (Mb[mrow[i] + key] != (MT)0);
      float e = mk ? 0.f : __expf(acc[i] * 0.125f);
      lsum[i] += e;
    }
  }
#pragma unroll
  for (int i = 0; i < 4; ++i) {
    lsum[i] += __shfl_xor(lsum[i], 1);
    lsum[i] += __shfl_xor(lsum[i], 2);
    lsum[i] += __shfl_xor(lsum[i], 4);
    lsum[i] += __shfl_xor(lsum[i], 8);
  }
  float rinv[4];
#pragma unroll
  for (int i = 0; i < 4; ++i) rinv[i] = 1.0f / lsum[i];

  // ---- pass 2: attn write + PV ----
  f32x4 oacc[4];
#pragma unroll
  for (int db = 0; db < 4; ++db) {
    oacc[db][0] = 0.f; oacc[db][1] = 0.f; oacc[db][2] = 0.f; oacc[db][3] = 0.f;
  }

  for (int kc = 0; kc < S_ / 32; ++kc) {
    int k0 = kc * 32;
#pragma unroll
    for (int sub = 0; sub < 2; ++sub) {
      int key = k0 + sub * 16 + lo;
      const unsigned short* kr = Kb + (size_t)key * D_ + hi * 8;
      bf16x8 b0 = *reinterpret_cast<const bf16x8*>(kr);
      bf16x8 b1 = *reinterpret_cast<const bf16x8*>(kr + 32);
      f32x4 acc = {0.f, 0.f, 0.f, 0.f};
      acc = __builtin_amdgcn_mfma_f32_16x16x32_bf16(aq[0], b0, acc, 0, 0, 0);
      acc = __builtin_amdgcn_mfma_f32_16x16x32_bf16(aq[1], b1, acc, 0, 0, 0);
#pragma unroll
      for (int i = 0; i < 4; ++i) {
        bool mk = (Mb[mrow[i] + key] != (MT)0);
        float p = mk ? 0.f : __expf(acc[i] * 0.125f) * rinv[i];
        __builtin_nontemporal_store(p, prow[i] + key);
        Pl[(hi * 4 + i) * 40 + sub * 16 + lo] = f2bf(p);
      }
    }
    // PV: A = P (rows=queries=lo, k over keys hi*8+j), B = Vt (cols=d=lo)
    bf16x8 pa = *reinterpret_cast<const bf16x8*>(Pl + lo * 40 + hi * 8);
#pragma unroll
    for (int db = 0; db < 4; ++db) {
      const unsigned short* vp = Vtb + (size_t)(db * 16 + lo) * S_ + k0 + hi * 8;
      bf16x8 bv = *reinterpret_cast<const bf16x8*>(vp);
      oacc[db] = __builtin_amdgcn_mfma_f32_16x16x32_bf16(pa, bv, oacc[db], 0, 0, 0);
    }
  }

#pragma unroll
  for (int db = 0; db < 4; ++db)
#pragma unroll
    for (int i = 0; i < 4; ++i)
      __builtin_nontemporal_store(oacc[db][i],
          outO + (size_t)(q0 + hi * 4 + i) * D_ + db * 16 + lo);
}

__global__ __launch_bounds__(256) void attn_main(
    const float* __restrict__ Q, const unsigned short* __restrict__ Kbf,
    const void* __restrict__ M, const unsigned short* __restrict__ Vt,
    const int* __restrict__ flag, float* __restrict__ Out) {
  __shared__ __align__(16) unsigned short Pl[4][16][40];
  int wg = blockIdx.x;                      // 1024 wgs
  int vdx = (wg & 7) * 128 + (wg >> 3);     // XCD-contiguous remap (bijective)
  int b = vdx >> 5;
  int qt = vdx & 31;
  int wave = threadIdx.x >> 6;
  int lane = threadIdx.x & 63;
  int q0 = qt * 64 + wave * 16;

  const float* Qb = Q + (size_t)b * S_ * D_;
  const unsigned short* Kb = Kbf + (size_t)b * S_ * D_;
  const unsigned short* Vtb = Vt + (size_t)b * D_ * S_;
  float* outO = Out + (size_t)b * S_ * D_;
  float* outP = Out + (size_t)B_ * S_ * D_ + (size_t)b * S_ * S_;
  int mode = *flag;

  if (mode == 0)
    attn_run<uint8_t>(Qb, Kb, (const uint8_t*)M + (size_t)b * S_ * S_, Vtb, outO, outP, q0, lane, &Pl[wave][0][0]);
  else if (mode == 1)
    attn_run<int>(Qb, Kb, (const int*)M + (size_t)b * S_ * S_, Vtb, outO, outP, q0, lane, &Pl[wave][0][0]);
  else
    attn_run<float>(Qb, Kb, (const float*)M + (size_t)b * S_ * S_, Vtb, outO, outP, q0, lane, &Pl[wave][0][0]);
}

extern "C" void kernel_launch(void* const* d_in, const int* in_sizes, int n_in,
                              void* d_out, int out_size, void* d_ws, size_t ws_size,
                              hipStream_t stream) {
  const float* q = (const float*)d_in[0];
  const float* k = (const float*)d_in[1];
  const float* v = (const float*)d_in[2];
  const void*  m = d_in[3];
  float* out = (float*)d_out;

  // ws layout: [0] int flag; [256] Vt bf16 (B*D*S); [256+8.4M] Kbf bf16 (B*S*D)
  int* flag = (int*)d_ws;
  unsigned short* Vt  = (unsigned short*)((char*)d_ws + 256);
  unsigned short* Kbf = (unsigned short*)((char*)d_ws + 256 + (size_t)B_ * D_ * S_ * 2);
  // requires ws_size >= ~16.8 MB

  detect_mask<<<1, 64, 0, stream>>>((const unsigned*)m, flag);
  cast_k<<<(B_ * S_ * D_) / (256 * 4), 256, 0, stream>>>(k, Kbf);
  transpose_v<<<dim3(S_ / 32, D_ / 32, B_), dim3(32, 8), 0, stream>>>(v, Vt);
  attn_main<<<B_ * (S_ / 64), 256, 0, stream>>>(q, Kbf, m, Vt, flag, out);
}

// Round 2
// 557.810 us; speedup vs baseline: 1.0549x; 1.0549x over previous
//
#include <hip/hip_runtime.h>
#include <hip/hip_bf16.h>
#include <stdint.h>

// B=32, S=2048, DK=DV=64, fp32 in/out. out = [output (B,S,64) | attn (B,S,S)].
// Two-pass MFMA attention with bit-packed mask:
//   prepass: detect mask dtype; pack mask -> 1 bit/elem (ws); cast K->bf16;
//            transpose-cast V -> Vt bf16.
//   main: per 16-query wave: pass1 QK^T -> row expsum (packed mask, broadcast
//         dword loads); pass2 recompute, stage p-tile in LDS, dwordx4 attn
//         stores, PV via mfma from the same LDS tile.

#define B_ 32
#define S_ 2048
#define D_ 64

typedef float   f32x4  __attribute__((ext_vector_type(4)));
typedef __bf16  bf16x8 __attribute__((ext_vector_type(8)));
typedef unsigned short u16x4 __attribute__((ext_vector_type(4)));

__device__ __forceinline__ unsigned short f2bf(float f) {
  unsigned u = __float_as_uint(f);
  u = (u + 0x7FFFu + ((u >> 16) & 1u)) >> 16;   // RNE
  return (unsigned short)u;
}

// ---------------- mask dtype detection ----------------
// flag: 0 = uint8 (numpy bool), 1 = 4-byte elems (int32 or float32)
__global__ void detect_mask(const unsigned* __restrict__ m, int* __restrict__ flag) {
  if (threadIdx.x == 0 && blockIdx.x == 0) {
    int wide = 1;   // plausible as 4-byte 0/1-ish data?
    for (int i = 0; i < 64; ++i) {
      unsigned w = m[i];
      wide &= (w <= 1u || w == 0x3F800000u);
    }
    *flag = wide ? 1 : 0;
  }
}

// ---------------- mask bit-pack: 32 elems -> 1 uint ----------------
__global__ void pack_mask(const void* __restrict__ M, const int* __restrict__ flag,
                          unsigned* __restrict__ Mp) {
  size_t t = (size_t)blockIdx.x * 256 + threadIdx.x;
  unsigned bits = 0;
  if (*flag == 0) {
    const uint4* p = (const uint4*)((const uint8_t*)M + t * 32);
    uint4 a = p[0], b = p[1];
    unsigned w[8] = {a.x, a.y, a.z, a.w, b.x, b.y, b.z, b.w};
#pragma unroll
    for (int i = 0; i < 8; ++i)
#pragma unroll
      for (int j = 0; j < 4; ++j)
        bits |= (unsigned)(((w[i] >> (8 * j)) & 0xFFu) != 0u) << (i * 4 + j);
  } else {
    const uint4* p = (const uint4*)((const unsigned*)M + t * 32);
#pragma unroll
    for (int i = 0; i < 8; ++i) {
      uint4 a = p[i];
      bits |= (unsigned)(a.x != 0u) << (i * 4 + 0);
      bits |= (unsigned)(a.y != 0u) << (i * 4 + 1);
      bits |= (unsigned)(a.z != 0u) << (i * 4 + 2);
      bits |= (unsigned)(a.w != 0u) << (i * 4 + 3);
    }
  }
  Mp[t] = bits;
}

// ---------------- K fp32 -> bf16 cast ----------------
__global__ void cast_k(const float* __restrict__ K, unsigned short* __restrict__ Kbf) {
  size_t i = ((size_t)blockIdx.x * 256 + threadIdx.x) * 4;
  f32x4 v = *reinterpret_cast<const f32x4*>(K + i);
  u16x4 o;
  o[0] = f2bf(v[0]); o[1] = f2bf(v[1]); o[2] = f2bf(v[2]); o[3] = f2bf(v[3]);
  *reinterpret_cast<u16x4*>(Kbf + i) = o;
}

// ---------------- V -> Vt (d-major) bf16 transpose ----------------
__global__ void transpose_v(const float* __restrict__ V, unsigned short* __restrict__ Vt) {
  __shared__ float tile[32][33];
  int b = blockIdx.z, k0 = blockIdx.x * 32, d0 = blockIdx.y * 32;
  int tx = threadIdx.x, ty = threadIdx.y;
  const float* src = V + ((size_t)b * S_ + k0) * D_ + d0;
  for (int r = 0; r < 4; ++r) {
    int yy = ty + r * 8;
    tile[yy][tx] = src[(size_t)yy * D_ + tx];
  }
  __syncthreads();
  unsigned short* dst = Vt + ((size_t)b * D_ + d0) * S_ + k0;
  for (int r = 0; r < 4; ++r) {
    int yy = ty + r * 8;
    dst[(size_t)yy * S_ + tx] = f2bf(tile[tx][yy]);
  }
}

// ---------------- main attention (packed-mask path) ----------------
__global__ __launch_bounds__(256) void attn_main2(
    const float* __restrict__ Q, const unsigned short* __restrict__ Kbf,
    const unsigned* __restrict__ Mp, const unsigned short* __restrict__ Vt,
    float* __restrict__ Out) {
  __shared__ __align__(16) float Pf[4][16][40];
  int wg = blockIdx.x;                      // 1024 wgs
  int vdx = (wg & 7) * 128 + (wg >> 3);     // XCD-contiguous remap (bijective)
  int b = vdx >> 5, qt = vdx & 31;
  int wave = threadIdx.x >> 6, lane = threadIdx.x & 63;
  int q0 = qt * 64 + wave * 16;
  const int lo = lane & 15, hi = lane >> 4;

  const float* Qb = Q + (size_t)b * S_ * D_;
  const unsigned short* Kb = Kbf + (size_t)b * S_ * D_;
  const unsigned short* Vtb = Vt + (size_t)b * D_ * S_;
  const unsigned* Mpb = Mp + (size_t)b * S_ * (S_ / 32);
  float* outO = Out + (size_t)b * S_ * D_;
  float* outP = Out + (size_t)B_ * S_ * D_ + (size_t)b * S_ * S_;

  // A-frags: Q rows = lo, k = kb*32 + hi*8 + j
  bf16x8 aq[2];
  {
    const float* qr = Qb + (size_t)(q0 + lo) * D_;
#pragma unroll
    for (int kb = 0; kb < 2; ++kb) {
      const float* p = qr + kb * 32 + hi * 8;
      f32x4 x = *reinterpret_cast<const f32x4*>(p);
      f32x4 y = *reinterpret_cast<const f32x4*>(p + 4);
      bf16x8 a;
      a[0] = (__bf16)x[0]; a[1] = (__bf16)x[1]; a[2] = (__bf16)x[2]; a[3] = (__bf16)x[3];
      a[4] = (__bf16)y[0]; a[5] = (__bf16)y[1]; a[6] = (__bf16)y[2]; a[7] = (__bf16)y[3];
      aq[kb] = a;
    }
  }

  // packed-mask row bases; D layout: col=lane&15 (key), row=(lane>>4)*4+reg (query)
  const unsigned* mrow[4];
#pragma unroll
  for (int i = 0; i < 4; ++i)
    mrow[i] = Mpb + (size_t)(q0 + hi * 4 + i) * (S_ / 32);

  // ---- pass 1: denominators (32 keys / iter) ----
  float lsum[4] = {0.f, 0.f, 0.f, 0.f};
  for (int kc = 0; kc < S_ / 32; ++kc) {
    const unsigned short* kr = Kb + (size_t)(kc * 32 + lo) * D_ + hi * 8;
    bf16x8 b0 = *reinterpret_cast<const bf16x8*>(kr);
    bf16x8 b1 = *reinterpret_cast<const bf16x8*>(kr + 32);
    bf16x8 c0 = *reinterpret_cast<const bf16x8*>(kr + 16 * D_);
    bf16x8 c1 = *reinterpret_cast<const bf16x8*>(kr + 16 * D_ + 32);
    f32x4 a0 = {0.f, 0.f, 0.f, 0.f}, a1 = {0.f, 0.f, 0.f, 0.f};
    a0 = __builtin_amdgcn_mfma_f32_16x16x32_bf16(aq[0], b0, a0, 0, 0, 0);
    a0 = __builtin_amdgcn_mfma_f32_16x16x32_bf16(aq[1], b1, a0, 0, 0, 0);
    a1 = __builtin_amdgcn_mfma_f32_16x16x32_bf16(aq[0], c0, a1, 0, 0, 0);
    a1 = __builtin_amdgcn_mfma_f32_16x16x32_bf16(aq[1], c1, a1, 0, 0, 0);
#pragma unroll
    for (int i = 0; i < 4; ++i) {
      unsigned mw = mrow[i][kc];
      float e0 = ((mw >> lo) & 1u) ? 0.f : __expf(a0[i] * 0.125f);
      float e1 = ((mw >> (16 + lo)) & 1u) ? 0.f : __expf(a1[i] * 0.125f);
      lsum[i] += e0 + e1;
    }
  }
#pragma unroll
  for (int i = 0; i < 4; ++i) {
    lsum[i] += __shfl_xor(lsum[i], 1);
    lsum[i] += __shfl_xor(lsum[i], 2);
    lsum[i] += __shfl_xor(lsum[i], 4);
    lsum[i] += __shfl_xor(lsum[i], 8);
  }
  float rinv[4];
#pragma unroll
  for (int i = 0; i < 4; ++i) rinv[i] = 1.0f / lsum[i];

  // ---- pass 2: attn write + PV ----
  f32x4 oacc[4];
#pragma unroll
  for (int db = 0; db < 4; ++db) {
    oacc[db][0] = 0.f; oacc[db][1] = 0.f; oacc[db][2] = 0.f; oacc[db][3] = 0.f;
  }
  float* Pfw = &Pf[wave][0][0];
  const int srow = lane >> 2, scol = (lane & 3) * 4;
  float* sp = outP + (size_t)(q0 + srow) * S_;

  for (int kc = 0; kc < S_ / 32; ++kc) {
    int k0 = kc * 32;
    const unsigned short* kr = Kb + (size_t)(k0 + lo) * D_ + hi * 8;
    bf16x8 b0 = *reinterpret_cast<const bf16x8*>(kr);
    bf16x8 b1 = *reinterpret_cast<const bf16x8*>(kr + 32);
    bf16x8 c0 = *reinterpret_cast<const bf16x8*>(kr + 16 * D_);
    bf16x8 c1 = *reinterpret_cast<const bf16x8*>(kr + 16 * D_ + 32);
    f32x4 a0 = {0.f, 0.f, 0.f, 0.f}, a1 = {0.f, 0.f, 0.f, 0.f};
    a0 = __builtin_amdgcn_mfma_f32_16x16x32_bf16(aq[0], b0, a0, 0, 0, 0);
    a0 = __builtin_amdgcn_mfma_f32_16x16x32_bf16(aq[1], b1, a0, 0, 0, 0);
    a1 = __builtin_amdgcn_mfma_f32_16x16x32_bf16(aq[0], c0, a1, 0, 0, 0);
    a1 = __builtin_amdgcn_mfma_f32_16x16x32_bf16(aq[1], c1, a1, 0, 0, 0);

#pragma unroll
    for (int i = 0; i < 4; ++i) {
      unsigned mw = mrow[i][kc];
      float p0 = ((mw >> lo) & 1u) ? 0.f : __expf(a0[i] * 0.125f) * rinv[i];
      float p1 = ((mw >> (16 + lo)) & 1u) ? 0.f : __expf(a1[i] * 0.125f) * rinv[i];
      Pfw[(hi * 4 + i) * 40 + lo] = p0;
      Pfw[(hi * 4 + i) * 40 + 16 + lo] = p1;
    }
    // wave-private tile: compiler inserts lgkmcnt waits; no barrier needed.

    // attn store: 2x dwordx4 per lane, 64B contiguous per 4-lane row group
    f32x4 t0 = *reinterpret_cast<const f32x4*>(&Pfw[srow * 40 + scol]);
    f32x4 t1 = *reinterpret_cast<const f32x4*>(&Pfw[srow * 40 + 16 + scol]);
    __builtin_nontemporal_store(t0, reinterpret_cast<f32x4*>(sp + k0 + scol));
    __builtin_nontemporal_store(t1, reinterpret_cast<f32x4*>(sp + k0 + 16 + scol));

    // PV: A = P rows=lo, k = hi*8+j ; B = Vt cols=d=lo, same k pattern
    f32x4 pf0 = *reinterpret_cast<const f32x4*>(&Pfw[lo * 40 + hi * 8]);
    f32x4 pf1 = *reinterpret_cast<const f32x4*>(&Pfw[lo * 40 + hi * 8 + 4]);
    bf16x8 pa;
    pa[0] = (__bf16)pf0[0]; pa[1] = (__bf16)pf0[1]; pa[2] = (__bf16)pf0[2]; pa[3] = (__bf16)pf0[3];
    pa[4] = (__bf16)pf1[0]; pa[5] = (__bf16)pf1[1]; pa[6] = (__bf16)pf1[2]; pa[7] = (__bf16)pf1[3];
#pragma unroll
    for (int db = 0; db < 4; ++db) {
      const unsigned short* vp = Vtb + (size_t)(db * 16 + lo) * S_ + k0 + hi * 8;
      bf16x8 bv = *reinterpret_cast<const bf16x8*>(vp);
      oacc[db] = __builtin_amdgcn_mfma_f32_16x16x32_bf16(pa, bv, oacc[db], 0, 0, 0);
    }
  }

#pragma unroll
  for (int db = 0; db < 4; ++db)
#pragma unroll
    for (int i = 0; i < 4; ++i)
      __builtin_nontemporal_store(oacc[db][i],
          outO + (size_t)(q0 + hi * 4 + i) * D_ + db * 16 + lo);
}

// ================= fallback (round-1 path, raw mask) =================
template <typename MT>
__device__ __forceinline__ void attn_run(
    const float* __restrict__ Qb, const unsigned short* __restrict__ Kb,
    const MT* __restrict__ Mb, const unsigned short* __restrict__ Vtb,
    float* __restrict__ outO, float* __restrict__ outP,
    int q0, int lane, unsigned short* __restrict__ Pl) {
  const int lo = lane & 15, hi = lane >> 4;
  bf16x8 aq[2];
  {
    const float* qr = Qb + (size_t)(q0 + lo) * D_;
#pragma unroll
    for (int kb = 0; kb < 2; ++kb) {
      const float* p = qr + kb * 32 + hi * 8;
      f32x4 x = *reinterpret_cast<const f32x4*>(p);
      f32x4 y = *reinterpret_cast<const f32x4*>(p + 4);
      bf16x8 a;
      a[0] = (__bf16)x[0]; a[1] = (__bf16)x[1]; a[2] = (__bf16)x[2]; a[3] = (__bf16)x[3];
      a[4] = (__bf16)y[0]; a[5] = (__bf16)y[1]; a[6] = (__bf16)y[2]; a[7] = (__bf16)y[3];
      aq[kb] = a;
    }
  }
  size_t mrow[4]; float* prow[4];
#pragma unroll
  for (int i = 0; i < 4; ++i) {
    int q = q0 + hi * 4 + i;
    mrow[i] = (size_t)q * S_; prow[i] = outP + (size_t)q * S_;
  }
  float lsum[4] = {0.f, 0.f, 0.f, 0.f};
  for (int kc = 0; kc < S_ / 16; ++kc) {
    int key = kc * 16 + lo;
    const unsigned short* kr = Kb + (size_t)key * D_ + hi * 8;
    bf16x8 b0 = *reinterpret_cast<const bf16x8*>(kr);
    bf16x8 b1 = *reinterpret_cast<const bf16x8*>(kr + 32);
    f32x4 acc = {0.f, 0.f, 0.f, 0.f};
    acc = __builtin_amdgcn_mfma_f32_16x16x32_bf16(aq[0], b0, acc, 0, 0, 0);
    acc = __builtin_amdgcn_mfma_f32_16x16x32_bf16(aq[1], b1, acc, 0, 0, 0);
#pragma unroll
    for (int i = 0; i < 4; ++i) {
      bool mk = (Mb[mrow[i] + key] != (MT)0);
      lsum[i] += mk ? 0.f : __expf(acc[i] * 0.125f);
    }
  }
#pragma unroll
  for (int i = 0; i < 4; ++i) {
    lsum[i] += __shfl_xor(lsum[i], 1);
    lsum[i] += __shfl_xor(lsum[i], 2);
    lsum[i] += __shfl_xor(lsum[i], 4);
    lsum[i] += __shfl_xor(lsum[i], 8);
  }
  float rinv[4];
#pragma unroll
  for (int i = 0; i < 4; ++i) rinv[i] = 1.0f / lsum[i];
  f32x4 oacc[4];
#pragma unroll
  for (int db = 0; db < 4; ++db) {
    oacc[db][0] = 0.f; oacc[db][1] = 0.f; oacc[db][2] = 0.f; oacc[db][3] = 0.f;
  }
  for (int kc = 0; kc < S_ / 32; ++kc) {
    int k0 = kc * 32;
#pragma unroll
    for (int sub = 0; sub < 2; ++sub) {
      int key = k0 + sub * 16 + lo;
      const unsigned short* kr = Kb + (size_t)key * D_ + hi * 8;
      bf16x8 b0 = *reinterpret_cast<const bf16x8*>(kr);
      bf16x8 b1 = *reinterpret_cast<const bf16x8*>(kr + 32);
      f32x4 acc = {0.f, 0.f, 0.f, 0.f};
      acc = __builtin_amdgcn_mfma_f32_16x16x32_bf16(aq[0], b0, acc, 0, 0, 0);
      acc = __builtin_amdgcn_mfma_f32_16x16x32_bf16(aq[1], b1, acc, 0, 0, 0);
#pragma unroll
      for (int i = 0; i < 4; ++i) {
        bool mk = (Mb[mrow[i] + key] != (MT)0);
        float p = mk ? 0.f : __expf(acc[i] * 0.125f) * rinv[i];
        __builtin_nontemporal_store(p, prow[i] + key);
        Pl[(hi * 4 + i) * 40 + sub * 16 + lo] = f2bf(p);
      }
    }
    bf16x8 pa = *reinterpret_cast<const bf16x8*>(Pl + lo * 40 + hi * 8);
#pragma unroll
    for (int db = 0; db < 4; ++db) {
      const unsigned short* vp = Vtb + (size_t)(db * 16 + lo) * S_ + k0 + hi * 8;
      bf16x8 bv = *reinterpret_cast<const bf16x8*>(vp);
      oacc[db] = __builtin_amdgcn_mfma_f32_16x16x32_bf16(pa, bv, oacc[db], 0, 0, 0);
    }
  }
#pragma unroll
  for (int db = 0; db < 4; ++db)
#pragma unroll
    for (int i = 0; i < 4; ++i)
      __builtin_nontemporal_store(oacc[db][i],
          outO + (size_t)(q0 + hi * 4 + i) * D_ + db * 16 + lo);
}

__global__ __launch_bounds__(256) void attn_main(
    const float* __restrict__ Q, const unsigned short* __restrict__ Kbf,
    const void* __restrict__ M, const unsigned short* __restrict__ Vt,
    const int* __restrict__ flag, float* __restrict__ Out) {
  __shared__ __align__(16) unsigned short Pl[4][16][40];
  int wg = blockIdx.x;
  int vdx = (wg & 7) * 128 + (wg >> 3);
  int b = vdx >> 5, qt = vdx & 31;
  int wave = threadIdx.x >> 6, lane = threadIdx.x & 63;
  int q0 = qt * 64 + wave * 16;
  const float* Qb = Q + (size_t)b * S_ * D_;
  const unsigned short* Kb = Kbf + (size_t)b * S_ * D_;
  const unsigned short* Vtb = Vt + (size_t)b * D_ * S_;
  float* outO = Out + (size_t)b * S_ * D_;
  float* outP = Out + (size_t)B_ * S_ * D_ + (size_t)b * S_ * S_;
  if (*flag == 0)
    attn_run<uint8_t>(Qb, Kb, (const uint8_t*)M + (size_t)b * S_ * S_, Vtb, outO, outP, q0, lane, &Pl[wave][0][0]);
  else
    attn_run<int>(Qb, Kb, (const int*)M + (size_t)b * S_ * S_, Vtb, outO, outP, q0, lane, &Pl[wave][0][0]);
}

extern "C" void kernel_launch(void* const* d_in, const int* in_sizes, int n_in,
                              void* d_out, int out_size, void* d_ws, size_t ws_size,
                              hipStream_t stream) {
  const float* q = (const float*)d_in[0];
  const float* k = (const float*)d_in[1];
  const float* v = (const float*)d_in[2];
  const void*  m = d_in[3];
  float* out = (float*)d_out;

  // ws layout: [0] flag; [256] Vt bf16 (8MB); [+8MB] Kbf bf16 (8MB); [+8MB] Mp (16MB)
  int* flag = (int*)d_ws;
  unsigned short* Vt  = (unsigned short*)((char*)d_ws + 256);
  unsigned short* Kbf = (unsigned short*)((char*)d_ws + 256 + (size_t)B_ * D_ * S_ * 2);
  unsigned*       Mp  = (unsigned*)((char*)d_ws + 256 + (size_t)B_ * D_ * S_ * 4);
  const size_t need = 256 + (size_t)B_ * D_ * S_ * 4 + (size_t)B_ * S_ * (S_ / 32) * 4;

  detect_mask<<<1, 64, 0, stream>>>((const unsigned*)m, flag);
  cast_k<<<(B_ * S_ * D_) / (256 * 4), 256, 0, stream>>>(k, Kbf);
  transpose_v<<<dim3(S_ / 32, D_ / 32, B_), dim3(32, 8), 0, stream>>>(v, Vt);

  if (ws_size >= need) {
    pack_mask<<<(B_ * S_ * (S_ / 32)) / 256, 256, 0, stream>>>(m, flag, Mp);
    attn_main2<<<B_ * (S_ / 64), 256, 0, stream>>>(q, Kbf, Mp, Vt, out);
  } else {
    attn_main<<<B_ * (S_ / 64), 256, 0, stream>>>(q, Kbf, m, Vt, flag, out);
  }
}

// Round 3
// 355.846 us; speedup vs baseline: 1.6537x; 1.5676x over previous
//
#include <hip/hip_runtime.h>
#include <hip/hip_bf16.h>
#include <stdint.h>

// B=32, S=2048, DK=DV=64, fp32 in/out. out = [output (B,S,64) | attn (B,S,S)].
// Two-pass MFMA attention, WG-cooperative double-buffered LDS staging:
//   prepass: detect mask dtype; pack mask 1 bit/elem; K->bf16; V -> Vt bf16 (d-major).
//   main (per WG = 4 waves = 64 queries):
//     pass1: staged K tiles (32 keys), QK^T MFMA, masked exp -> row sums
//     pass2: staged K+Vt tiles, recompute, swizzled LDS p-tile, dwordx4 attn
//            stores, PV MFMA from LDS.
// All LDS tiles XOR-swizzled at 16B-slot granularity; global_load_lds sources
// pre-inverse-swizzled (linear LDS dest requirement).

#define B_ 32
#define S_ 2048
#define D_ 64

typedef float   f32x4  __attribute__((ext_vector_type(4)));
typedef __bf16  bf16x8 __attribute__((ext_vector_type(8)));
typedef unsigned short u16x4 __attribute__((ext_vector_type(4)));

__device__ __forceinline__ unsigned short f2bf(float f) {
  unsigned u = __float_as_uint(f);
  u = (u + 0x7FFFu + ((u >> 16) & 1u)) >> 16;   // RNE
  return (unsigned short)u;
}

__device__ __forceinline__ void load_lds16(const void* g, void* l) {
  __builtin_amdgcn_global_load_lds(
      (const __attribute__((address_space(1))) unsigned*)g,
      (__attribute__((address_space(3))) unsigned*)l, 16, 0, 0);
}

// ---------------- mask dtype detection ----------------
__global__ void detect_mask(const unsigned* __restrict__ m, int* __restrict__ flag) {
  if (threadIdx.x == 0 && blockIdx.x == 0) {
    int wide = 1;
    for (int i = 0; i < 64; ++i) {
      unsigned w = m[i];
      wide &= (w <= 1u || w == 0x3F800000u);
    }
    *flag = wide ? 1 : 0;
  }
}

// ---------------- mask bit-pack: 32 elems -> 1 uint ----------------
__global__ void pack_mask(const void* __restrict__ M, const int* __restrict__ flag,
                          unsigned* __restrict__ Mp) {
  size_t t = (size_t)blockIdx.x * 256 + threadIdx.x;
  unsigned bits = 0;
  if (*flag == 0) {
    const uint4* p = (const uint4*)((const uint8_t*)M + t * 32);
    uint4 a = p[0], b = p[1];
    unsigned w[8] = {a.x, a.y, a.z, a.w, b.x, b.y, b.z, b.w};
#pragma unroll
    for (int i = 0; i < 8; ++i)
#pragma unroll
      for (int j = 0; j < 4; ++j)
        bits |= (unsigned)(((w[i] >> (8 * j)) & 0xFFu) != 0u) << (i * 4 + j);
  } else {
    const uint4* p = (const uint4*)((const unsigned*)M + t * 32);
#pragma unroll
    for (int i = 0; i < 8; ++i) {
      uint4 a = p[i];
      bits |= (unsigned)(a.x != 0u) << (i * 4 + 0);
      bits |= (unsigned)(a.y != 0u) << (i * 4 + 1);
      bits |= (unsigned)(a.z != 0u) << (i * 4 + 2);
      bits |= (unsigned)(a.w != 0u) << (i * 4 + 3);
    }
  }
  Mp[t] = bits;
}

// ---------------- K fp32 -> bf16 cast ----------------
__global__ void cast_k(const float* __restrict__ K, unsigned short* __restrict__ Kbf) {
  size_t i = ((size_t)blockIdx.x * 256 + threadIdx.x) * 4;
  f32x4 v = *reinterpret_cast<const f32x4*>(K + i);
  u16x4 o;
  o[0] = f2bf(v[0]); o[1] = f2bf(v[1]); o[2] = f2bf(v[2]); o[3] = f2bf(v[3]);
  *reinterpret_cast<u16x4*>(Kbf + i) = o;
}

// ---------------- V -> Vt (d-major) bf16 transpose ----------------
__global__ void transpose_v(const float* __restrict__ V, unsigned short* __restrict__ Vt) {
  __shared__ float tile[32][33];
  int b = blockIdx.z, k0 = blockIdx.x * 32, d0 = blockIdx.y * 32;
  int tx = threadIdx.x, ty = threadIdx.y;
  const float* src = V + ((size_t)b * S_ + k0) * D_ + d0;
  for (int r = 0; r < 4; ++r) {
    int yy = ty + r * 8;
    tile[yy][tx] = src[(size_t)yy * D_ + tx];
  }
  __syncthreads();
  unsigned short* dst = Vt + ((size_t)b * D_ + d0) * S_ + k0;
  for (int r = 0; r < 4; ++r) {
    int yy = ty + r * 8;
    dst[(size_t)yy * S_ + tx] = f2bf(tile[tx][yy]);
  }
}

// ---------------- main attention ----------------
__global__ __launch_bounds__(256, 4) void attn_main3(
    const float* __restrict__ Q, const unsigned short* __restrict__ Kbf,
    const unsigned* __restrict__ Mp, const unsigned short* __restrict__ Vt,
    float* __restrict__ Out) {
  // K tile: [32 keys][64 d] bf16, 8 slots(16B)/row, swz slot^=(row&7)
  // Vt tile: [64 d][32 keys] bf16, 4 slots/row, swz slot^=(row&3)
  // Pf (per wave): [16 q][32 keys] f32, 8 slots/row, swz slot^=(row&7)
  __shared__ __align__(16) unsigned short Klds[2][32 * 64];
  __shared__ __align__(16) unsigned short Vlds[2][64 * 32];
  __shared__ __align__(16) float Pf[4][16 * 32];

  int wg = blockIdx.x;                       // 1024 wgs
  int vdx = (wg & 7) * 128 + (wg >> 3);      // XCD-contiguous remap (bijective)
  int b = vdx >> 5, qt = vdx & 31;
  int wave = threadIdx.x >> 6, lane = threadIdx.x & 63;
  int q0 = qt * 64 + wave * 16;
  const int lo = lane & 15, hi = lane >> 4;
  const int t = threadIdx.x;

  const float* Qb = Q + (size_t)b * S_ * D_;
  const unsigned short* Kb = Kbf + (size_t)b * S_ * D_;
  const unsigned short* Vtb = Vt + (size_t)b * D_ * S_;
  const unsigned* Mpb = Mp + (size_t)b * S_ * (S_ / 32);
  float* outO = Out + (size_t)b * S_ * D_;
  float* outP = Out + (size_t)B_ * S_ * D_ + (size_t)b * S_ * S_;

  // staging addresses: thread t fills LDS 16B-slot t (linear); global source
  // is inverse-swizzled so that swizzled reads see the right data.
  const int krow = t >> 3, kj = (t & 7) ^ (krow & 7);
  const unsigned short* kgsrc = Kb + (size_t)krow * D_ + kj * 8;
  unsigned short* kdst0 = &Klds[0][t * 8];
  unsigned short* kdst1 = &Klds[1][t * 8];
  const int vrow = t >> 2, vj = (t & 3) ^ (vrow & 3);
  const unsigned short* vgsrc = Vtb + (size_t)vrow * S_ + vj * 8;
  unsigned short* vdst0 = &Vlds[0][t * 8];
  unsigned short* vdst1 = &Vlds[1][t * 8];

  // Q A-fragments: rows = lo, k = kb*32 + hi*8 + j
  bf16x8 aq[2];
  {
    const float* qr = Qb + (size_t)(q0 + lo) * D_;
#pragma unroll
    for (int kb = 0; kb < 2; ++kb) {
      const float* p = qr + kb * 32 + hi * 8;
      f32x4 x = *reinterpret_cast<const f32x4*>(p);
      f32x4 y = *reinterpret_cast<const f32x4*>(p + 4);
      bf16x8 a;
      a[0] = (__bf16)x[0]; a[1] = (__bf16)x[1]; a[2] = (__bf16)x[2]; a[3] = (__bf16)x[3];
      a[4] = (__bf16)y[0]; a[5] = (__bf16)y[1]; a[6] = (__bf16)y[2]; a[7] = (__bf16)y[3];
      aq[kb] = a;
    }
  }

  // packed-mask rows; D layout: col=lane&15 (key), row=(lane>>4)*4+reg (query)
  const unsigned* mrow[4];
#pragma unroll
  for (int i = 0; i < 4; ++i)
    mrow[i] = Mpb + (size_t)(q0 + hi * 4 + i) * (S_ / 32);

  // swizzled K-frag element offsets (row stride 64 elems, slot = 8 elems)
  const int sw7 = lo & 7, sw3 = lo & 3;
  const int offb0 = lo * 64 + ((hi ^ sw7) << 3);
  const int offb1 = lo * 64 + (((hi + 4) ^ sw7) << 3);
  const int offc0 = (16 + lo) * 64 + ((hi ^ sw7) << 3);
  const int offc1 = (16 + lo) * 64 + (((hi + 4) ^ sw7) << 3);

  // ================= pass 1: denominators =================
  float lsum[4] = {0.f, 0.f, 0.f, 0.f};
  unsigned mw[4];
#pragma unroll
  for (int i = 0; i < 4; ++i) mw[i] = mrow[i][0];
  load_lds16(kgsrc, kdst0);
  __syncthreads();

  for (int kc = 0; kc < S_ / 32; ++kc) {
    const unsigned short* kl = &Klds[kc & 1][0];
    if (kc < S_ / 32 - 1)
      load_lds16(kgsrc + (size_t)(kc + 1) * 32 * D_, (kc & 1) ? kdst0 : kdst1);
    unsigned mwn[4] = {mw[0], mw[1], mw[2], mw[3]};
    if (kc < S_ / 32 - 1) {
#pragma unroll
      for (int i = 0; i < 4; ++i) mwn[i] = mrow[i][kc + 1];
    }
    bf16x8 b0 = *reinterpret_cast<const bf16x8*>(kl + offb0);
    bf16x8 b1 = *reinterpret_cast<const bf16x8*>(kl + offb1);
    bf16x8 c0 = *reinterpret_cast<const bf16x8*>(kl + offc0);
    bf16x8 c1 = *reinterpret_cast<const bf16x8*>(kl + offc1);
    f32x4 a0 = {0.f, 0.f, 0.f, 0.f}, a1 = {0.f, 0.f, 0.f, 0.f};
    a0 = __builtin_amdgcn_mfma_f32_16x16x32_bf16(aq[0], b0, a0, 0, 0, 0);
    a0 = __builtin_amdgcn_mfma_f32_16x16x32_bf16(aq[1], b1, a0, 0, 0, 0);
    a1 = __builtin_amdgcn_mfma_f32_16x16x32_bf16(aq[0], c0, a1, 0, 0, 0);
    a1 = __builtin_amdgcn_mfma_f32_16x16x32_bf16(aq[1], c1, a1, 0, 0, 0);
#pragma unroll
    for (int i = 0; i < 4; ++i) {
      float e0 = ((mw[i] >> lo) & 1u) ? 0.f : __expf(a0[i] * 0.125f);
      float e1 = ((mw[i] >> (16 + lo)) & 1u) ? 0.f : __expf(a1[i] * 0.125f);
      lsum[i] += e0 + e1;
    }
#pragma unroll
    for (int i = 0; i < 4; ++i) mw[i] = mwn[i];
    __syncthreads();
  }

#pragma unroll
  for (int i = 0; i < 4; ++i) {
    lsum[i] += __shfl_xor(lsum[i], 1);
    lsum[i] += __shfl_xor(lsum[i], 2);
    lsum[i] += __shfl_xor(lsum[i], 4);
    lsum[i] += __shfl_xor(lsum[i], 8);
  }
  float rinv[4];
#pragma unroll
  for (int i = 0; i < 4; ++i) rinv[i] = 1.0f / lsum[i];

  // ================= pass 2: attn write + PV =================
  f32x4 oacc[4];
#pragma unroll
  for (int db = 0; db < 4; ++db) {
    oacc[db][0] = 0.f; oacc[db][1] = 0.f; oacc[db][2] = 0.f; oacc[db][3] = 0.f;
  }
  float* Pfw = &Pf[wave][0];
  const int srow = lane >> 2, sj = lane & 3;
  float* sp = outP + (size_t)(q0 + srow) * S_;
  // Pf swizzled offsets (floats; row stride 32 floats, slot = 4 floats)
  const int pw0a = ((lo >> 2));                // base col-slot of p0
  const int tr0 = srow * 32 + ((sj ^ (srow & 7)) << 2);
  const int tr1 = srow * 32 + (((sj + 4) ^ (srow & 7)) << 2);
  const int pr0 = lo * 32 + (((2 * hi) ^ sw7) << 2);
  const int pr1 = lo * 32 + (((2 * hi + 1) ^ sw7) << 2);

#pragma unroll
  for (int i = 0; i < 4; ++i) mw[i] = mrow[i][0];
  load_lds16(kgsrc, kdst0);
  load_lds16(vgsrc, vdst0);
  __syncthreads();

  for (int kc = 0; kc < S_ / 32; ++kc) {
    const unsigned short* kl = &Klds[kc & 1][0];
    const unsigned short* vl = &Vlds[kc & 1][0];
    if (kc < S_ / 32 - 1) {
      load_lds16(kgsrc + (size_t)(kc + 1) * 32 * D_, (kc & 1) ? kdst0 : kdst1);
      load_lds16(vgsrc + (kc + 1) * 32, (kc & 1) ? vdst0 : vdst1);
    }
    unsigned mwn[4] = {mw[0], mw[1], mw[2], mw[3]};
    if (kc < S_ / 32 - 1) {
#pragma unroll
      for (int i = 0; i < 4; ++i) mwn[i] = mrow[i][kc + 1];
    }
    bf16x8 b0 = *reinterpret_cast<const bf16x8*>(kl + offb0);
    bf16x8 b1 = *reinterpret_cast<const bf16x8*>(kl + offb1);
    bf16x8 c0 = *reinterpret_cast<const bf16x8*>(kl + offc0);
    bf16x8 c1 = *reinterpret_cast<const bf16x8*>(kl + offc1);
    f32x4 a0 = {0.f, 0.f, 0.f, 0.f}, a1 = {0.f, 0.f, 0.f, 0.f};
    a0 = __builtin_amdgcn_mfma_f32_16x16x32_bf16(aq[0], b0, a0, 0, 0, 0);
    a0 = __builtin_amdgcn_mfma_f32_16x16x32_bf16(aq[1], b1, a0, 0, 0, 0);
    a1 = __builtin_amdgcn_mfma_f32_16x16x32_bf16(aq[0], c0, a1, 0, 0, 0);
    a1 = __builtin_amdgcn_mfma_f32_16x16x32_bf16(aq[1], c1, a1, 0, 0, 0);

#pragma unroll
    for (int i = 0; i < 4; ++i) {
      int row = hi * 4 + i;
      float p0 = ((mw[i] >> lo) & 1u) ? 0.f : __expf(a0[i] * 0.125f) * rinv[i];
      float p1 = ((mw[i] >> (16 + lo)) & 1u) ? 0.f : __expf(a1[i] * 0.125f) * rinv[i];
      Pfw[row * 32 + ((pw0a ^ (row & 7)) << 2) + (lo & 3)] = p0;
      Pfw[row * 32 + (((pw0a + 4) ^ (row & 7)) << 2) + (lo & 3)] = p1;
    }
    // wave-private tile: compiler inserts lgkmcnt before dependent reads.

    // attn store: 2x dwordx4 per lane (64B contiguous per 4-lane group)
    f32x4 t0 = *reinterpret_cast<const f32x4*>(Pfw + tr0);
    f32x4 t1 = *reinterpret_cast<const f32x4*>(Pfw + tr1);
    __builtin_nontemporal_store(t0, reinterpret_cast<f32x4*>(sp + kc * 32 + sj * 4));
    __builtin_nontemporal_store(t1, reinterpret_cast<f32x4*>(sp + kc * 32 + 16 + sj * 4));

    // PV: A = P rows=lo, k=hi*8+j ; B = Vt cols=d, same k pattern
    f32x4 pf0 = *reinterpret_cast<const f32x4*>(Pfw + pr0);
    f32x4 pf1 = *reinterpret_cast<const f32x4*>(Pfw + pr1);
    bf16x8 pa;
    pa[0] = (__bf16)pf0[0]; pa[1] = (__bf16)pf0[1]; pa[2] = (__bf16)pf0[2]; pa[3] = (__bf16)pf0[3];
    pa[4] = (__bf16)pf1[0]; pa[5] = (__bf16)pf1[1]; pa[6] = (__bf16)pf1[2]; pa[7] = (__bf16)pf1[3];
#pragma unroll
    for (int db = 0; db < 4; ++db) {
      bf16x8 bv = *reinterpret_cast<const bf16x8*>(vl + (db * 16 + lo) * 32 + ((hi ^ sw3) << 3));
      oacc[db] = __builtin_amdgcn_mfma_f32_16x16x32_bf16(pa, bv, oacc[db], 0, 0, 0);
    }
#pragma unroll
    for (int i = 0; i < 4; ++i) mw[i] = mwn[i];
    __syncthreads();
  }

#pragma unroll
  for (int db = 0; db < 4; ++db)
#pragma unroll
    for (int i = 0; i < 4; ++i)
      __builtin_nontemporal_store(oacc[db][i],
          outO + (size_t)(q0 + hi * 4 + i) * D_ + db * 16 + lo);
}

extern "C" void kernel_launch(void* const* d_in, const int* in_sizes, int n_in,
                              void* d_out, int out_size, void* d_ws, size_t ws_size,
                              hipStream_t stream) {
  const float* q = (const float*)d_in[0];
  const float* k = (const float*)d_in[1];
  const float* v = (const float*)d_in[2];
  const void*  m = d_in[3];
  float* out = (float*)d_out;

  // ws: [0] flag; [256] Vt bf16 (8MB); [+8MB] Kbf bf16 (8MB); [+8MB] Mp (16MB)
  int* flag = (int*)d_ws;
  unsigned short* Vt  = (unsigned short*)((char*)d_ws + 256);
  unsigned short* Kbf = (unsigned short*)((char*)d_ws + 256 + (size_t)B_ * D_ * S_ * 2);
  unsigned*       Mp  = (unsigned*)((char*)d_ws + 256 + (size_t)B_ * D_ * S_ * 4);

  detect_mask<<<1, 64, 0, stream>>>((const unsigned*)m, flag);
  cast_k<<<(B_ * S_ * D_) / (256 * 4), 256, 0, stream>>>(k, Kbf);
  transpose_v<<<dim3(S_ / 32, D_ / 32, B_), dim3(32, 8), 0, stream>>>(v, Vt);
  pack_mask<<<(B_ * S_ * (S_ / 32)) / 256, 256, 0, stream>>>(m, flag, Mp);
  attn_main3<<<B_ * (S_ / 64), 256, 0, stream>>>(q, Kbf, Mp, Vt, out);
}